// Round 6
// baseline (754.513 us; speedup 1.0000x reference)
//
#include <hip/hip_runtime.h>

// DeepSet trimmed-mean pipeline, fp16 MFMA path.
// ws layout (bytes), total ~339.3 MB:
//   X16   @ 0          (64 MB)   fp16 [65536][512]
//   H1    @ 64MB       (128 MB)  fp16 [65536][1024]
//   encT  @ 192MB      (128 MB)  fp16 [64][1024 h][1024 n]
//   W1T   @ 320MB      (1 MB)    fp16 [1024][512]
//   W2T   @ 321MB      (2 MB)    fp16 [1024][1024]
//   agg   @ 323MB      (256 KB)  f32 [64][1024]
//   nv,k  @ +512KB     (tiny)

typedef _Float16 half8  __attribute__((ext_vector_type(8)));
typedef _Float16 half4v __attribute__((ext_vector_type(4)));
typedef float    floatx4 __attribute__((ext_vector_type(4)));

#define GLD_LDS(g, l)                                                                     \
  __builtin_amdgcn_global_load_lds((const __attribute__((address_space(1))) void*)(g),    \
                                   (__attribute__((address_space(3))) void*)(l), 16, 0, 0)

// ---------------- P0: num_valid / k per batch ----------------
__global__ void prep_nv(const float* __restrict__ mask, int* __restrict__ nv_arr,
                        int* __restrict__ k_arr) {
  int b = blockIdx.x, lane = threadIdx.x;  // 64 threads
  const float4* mp = (const float4*)(mask + (b << 10));
  float s = 0.f;
#pragma unroll
  for (int i = 0; i < 4; ++i) {
    float4 v = mp[lane + i * 64];
    s += v.x + v.y + v.z + v.w;
  }
#pragma unroll
  for (int off = 32; off > 0; off >>= 1) s += __shfl_xor(s, off, 64);
  if (lane == 0) {
    int nv = (int)(s + 0.5f);
    int kk = (int)((float)nv * 0.1f);  // matches reference float32 * 0.1 -> int
    nv_arr[b] = nv;
    k_arr[b] = kk;
  }
}

// ---------------- P1 (merged): X conv (+ragged skip) & both W transposes --------
__device__ __forceinline__ void transpose_body(const float* __restrict__ W,
                                               _Float16* __restrict__ WT, int R, int C,
                                               int r0, int c0, _Float16 (*tile)[65]) {
  for (int i = threadIdx.x; i < 4096; i += 256) {
    int r = i >> 6, c = i & 63;
    tile[r][c] = (_Float16)W[(size_t)(r0 + r) * C + c0 + c];
  }
  __syncthreads();
  for (int i = threadIdx.x; i < 4096; i += 256) {
    int c = i >> 6, r = i & 63;
    WT[(size_t)(c0 + c) * R + r0 + r] = tile[r][c];
  }
}

__global__ __launch_bounds__(256) void preprocess(
    const float* __restrict__ X, _Float16* __restrict__ X16,
    const float* __restrict__ W1, _Float16* __restrict__ W1T,
    const float* __restrict__ W2, _Float16* __restrict__ W2T,
    const int* __restrict__ nv_arr) {
  __shared__ _Float16 tile[64][65];
  int bid = blockIdx.x;
  if (bid < 16384) {
    // conv X fp32->fp16; block covers rows 4*bid..4*bid+3 of one batch.
    int n0 = (bid << 2) & 1023;
    int batch = bid >> 8;
    int nv = nv_arr[batch];
    if (n0 >= ((nv + 127) & ~127)) return;  // rows never read by GEMM1
    int i = (bid * 256 + threadIdx.x) * 8;
    float4 a = *(const float4*)(X + i);
    float4 c = *(const float4*)(X + i + 4);
    half8 h;
    h[0] = (_Float16)a.x; h[1] = (_Float16)a.y; h[2] = (_Float16)a.z; h[3] = (_Float16)a.w;
    h[4] = (_Float16)c.x; h[5] = (_Float16)c.y; h[6] = (_Float16)c.z; h[7] = (_Float16)c.w;
    *(half8*)(X16 + i) = h;
  } else if (bid < 16384 + 128) {
    int id = bid - 16384;  // W1: R=512, C=1024; 8 x 16 tiles
    transpose_body(W1, W1T, 512, 1024, (id & 7) * 64, (id >> 3) * 64, tile);
  } else {
    int id = bid - 16512;  // W2: R=1024, C=1024; 16 x 16 tiles
    transpose_body(W2, W2T, 1024, 1024, (id & 15) * 64, (id >> 4) * 64, tile);
  }
}

// ---------------- GEMM: D[i][j] = sum_k Aop[i][k]*Bop[j][k] ----------------
// 128x128 tile, BK=64 (32 MFMA per barrier). [R4 config — measured best: 154 us,
// 0 bank conflicts, FETCH ~88 MB. BK=32 dbuf (R5) regressed: conflicts returned.]
// XCD-aware grid: with round-robin workgroup->XCD (bid%8), the 8 blocks sharing a
// fat-operand tile are consecutive slots on ONE XCD: fat = ((bid>>6)<<3)|(bid&7),
// thin = (bid>>3)&7 -> fat tile fetched into exactly one XCD L2, once.
// MODE 1: i=h(thin), j=m(fat). out = relu(D+bias[i]) -> H1[m][h].
// MODE 2: i=m(fat), j=h(thin). out = D + bias[j] -> encT[b][h][n].
// LDS: 128 rows x 64 halves; 16B chunk c of row r at slot (c ^ (r&7)), permutation
// applied to the GLOBAL source address (global_load_lds lands lane-contiguous).
template <int KDIM, int MODE>
__global__ __launch_bounds__(256, 3) void gemm_kernel(
    const _Float16* __restrict__ Aop, const _Float16* __restrict__ Bop,
    const float* __restrict__ bias, const int* __restrict__ nv_arr,
    _Float16* __restrict__ outp) {
  __shared__ __align__(16) _Float16 ldsA[128 * 64];
  __shared__ __align__(16) _Float16 ldsB[128 * 64];
  int i0, j0;
  int bid = blockIdx.x;
  int fat = (((bid >> 6) << 3) | (bid & 7)) * 128;
  int thin = ((bid >> 3) & 7) * 128;
  if (MODE == 1) {
    i0 = thin; j0 = fat;
    if ((j0 & 1023) >= nv_arr[j0 >> 10]) return;
  } else {
    i0 = fat; j0 = thin;
    if ((i0 & 1023) >= nv_arr[i0 >> 10]) return;
  }
  const int t = threadIdx.x, lane = t & 63;
  const int wv = t >> 6, wi = wv & 1, wj = wv >> 1;
  const int lr = lane & 15, q = lane >> 4;

  floatx4 acc[4][4] = {};

  // staging: chunk idx = r*256 + t (r=0..3) per operand; row = idx>>3, slot = idx&7,
  // global chunk gch = slot ^ (row&7). gch is independent of r.
  const int gch = (t & 7) ^ ((t >> 3) & 7);
  const _Float16* gA[4];
  const _Float16* gB[4];
  _Float16* lA[4];
  _Float16* lB[4];
#pragma unroll
  for (int r = 0; r < 4; ++r) {
    int row = r * 32 + (t >> 3);
    gA[r] = Aop + (size_t)(i0 + row) * KDIM + gch * 8;
    gB[r] = Bop + (size_t)(j0 + row) * KDIM + gch * 8;
    lA[r] = ldsA + (r * 256 + (t & ~63)) * 8;
    lB[r] = ldsB + (r * 256 + (t & ~63)) * 8;
  }

  int aoff[4], boff[4];
#pragma unroll
  for (int mi = 0; mi < 4; ++mi) {
    int row = wi * 64 + mi * 16 + lr;
    aoff[mi] = row * 64 + ((q ^ (row & 7)) * 8);
  }
#pragma unroll
  for (int nj = 0; nj < 4; ++nj) {
    int row = wj * 64 + nj * 16 + lr;
    boff[nj] = row * 64 + ((q ^ (row & 7)) * 8);
  }

  for (int kt = 0; kt < KDIM / 64; ++kt) {
#pragma unroll
    for (int r = 0; r < 4; ++r) GLD_LDS(gA[r], lA[r]);
#pragma unroll
    for (int r = 0; r < 4; ++r) GLD_LDS(gB[r], lB[r]);
#pragma unroll
    for (int r = 0; r < 4; ++r) { gA[r] += 64; gB[r] += 64; }
    __syncthreads();
#pragma unroll
    for (int kk = 0; kk < 2; ++kk) {
      half8 af[4], bf[4];
#pragma unroll
      for (int mi = 0; mi < 4; ++mi) af[mi] = *(const half8*)&ldsA[aoff[mi] ^ (kk * 32)];
#pragma unroll
      for (int nj = 0; nj < 4; ++nj) bf[nj] = *(const half8*)&ldsB[boff[nj] ^ (kk * 32)];
#pragma unroll
      for (int mi = 0; mi < 4; ++mi)
#pragma unroll
        for (int nj = 0; nj < 4; ++nj)
          acc[mi][nj] =
              __builtin_amdgcn_mfma_f32_16x16x32_f16(af[mi], bf[nj], acc[mi][nj], 0, 0, 0);
    }
    __syncthreads();
  }

  // epilogue: lane holds rows i = base..base+3 (contiguous), col j = lr per 16x16 tile
  if (MODE == 1) {
#pragma unroll
    for (int mi = 0; mi < 4; ++mi) {
      int ih = i0 + wi * 64 + mi * 16 + q * 4;
      floatx4 bb = *(const floatx4*)&bias[ih];
#pragma unroll
      for (int nj = 0; nj < 4; ++nj) {
        int j = j0 + wj * 64 + nj * 16 + lr;
        floatx4 v = acc[mi][nj];
        half4v hv;
#pragma unroll
        for (int r = 0; r < 4; ++r) hv[r] = (_Float16)fmaxf(v[r] + bb[r], 0.f);
        *(half4v*)&outp[(size_t)j * 1024 + ih] = hv;  // H1[m][h..h+3]
      }
    }
  } else {
#pragma unroll
    for (int nj = 0; nj < 4; ++nj) {
      int j = j0 + wj * 64 + nj * 16 + lr;  // h
      float bj = bias[j];
#pragma unroll
      for (int mi = 0; mi < 4; ++mi) {
        int im = i0 + wi * 64 + mi * 16 + q * 4;  // m
        int bb = im >> 10, n = im & 1023;
        floatx4 v = acc[mi][nj];
        half4v hv;
#pragma unroll
        for (int r = 0; r < 4; ++r) hv[r] = (_Float16)(v[r] + bj);
        *(half4v*)&outp[((size_t)bb << 20) + ((size_t)j << 10) + (size_t)n] = hv;
      }
    }
  }
}

// ---------------- Trim v3: count-only histogram + in-register sums ----------------
// One wave per column (b,h). 1024 u32 count bins (16 KB/block -> 10 blocks/CU).
// Locate boundary bins from count scan; all sums (s(b1), s(b2), mid-sum) computed
// in-register via predicated wave reductions over the 16 loaded values/lane.
// Physical slot of logical uint4-chunk j of lane L: L*4 + (j ^ ((L>>1)&3))  (2-way
// free bank pattern for the b128 init/readback).
#define NB 1024
__global__ __launch_bounds__(256) void trim_kernel(const _Float16* __restrict__ encT,
                                                   const int* __restrict__ nv_arr,
                                                   const int* __restrict__ k_arr,
                                                   float* __restrict__ agg) {
  __shared__ unsigned int cnt[4 * NB];  // 16 KB, wave-private slices
  int t = threadIdx.x, lane = t & 63, w = t >> 6;
  int blk = blockIdx.x;
  int batch = blk >> 8;
  int h = ((blk & 255) << 2) + w;
  unsigned int* cw = cnt + w * NB;
  uint4* cp = (uint4*)cw;
  {
    uint4 z = {0u, 0u, 0u, 0u};
#pragma unroll
    for (int i = 0; i < 4; ++i) cp[lane * 4 + (i ^ ((lane >> 1) & 3))] = z;
  }

  int nv = nv_arr[batch], kk = k_arr[batch];
  const _Float16* col = encT + ((size_t)batch << 20) + ((size_t)h << 10);
  const uint4* p = (const uint4*)col + lane * 2;
  uint4 u0 = p[0], u1 = p[1];
  unsigned vals[8] = {u0.x, u0.y, u0.z, u0.w, u1.x, u1.y, u1.z, u1.w};
  int nvalid = nv - lane * 16;  // may be <=0 or >=16

  float vv[16];
  int bn[16];
#pragma unroll
  for (int d = 0; d < 8; ++d) {
    unsigned u = vals[d];
#pragma unroll
    for (int sub = 0; sub < 2; ++sub) {
      int idx = d * 2 + sub;
      unsigned short bits = (unsigned short)(sub ? (u >> 16) : (u & 0xffffu));
      _Float16 hvv;
      __builtin_memcpy(&hvv, &bits, 2);
      float v = (float)hvv;
      if (idx < nvalid) {
        v = fminf(fmaxf(v, -8.0f), 7.999f);
        int bin = (int)((v + 8.0f) * 64.0f);
        bin = min(NB - 1, bin);
        vv[idx] = v;
        bn[idx] = bin;
        int Lb = bin >> 4, jc = (bin >> 2) & 3;
        int phys = ((Lb << 2) + (jc ^ ((Lb >> 1) & 3))) * 4 + (bin & 3);
        atomicAdd(&cw[phys], 1u);
      } else {
        vv[idx] = 0.f;
        bn[idx] = -1;
      }
    }
  }

  // readback own 16 counts (logical bins [lane*16, lane*16+16))
  int c[16];
  {
    uint4 rb[4];
#pragma unroll
    for (int i = 0; i < 4; ++i) rb[i] = cp[lane * 4 + (i ^ ((lane >> 1) & 3))];
#pragma unroll
    for (int i = 0; i < 4; ++i) {
      c[4 * i] = (int)rb[i].x; c[4 * i + 1] = (int)rb[i].y;
      c[4 * i + 2] = (int)rb[i].z; c[4 * i + 3] = (int)rb[i].w;
    }
  }
  int ct = 0;
#pragma unroll
  for (int i = 0; i < 16; ++i) ct += c[i];
  // exclusive scan of chunk totals across lanes
  int ci = ct;
#pragma unroll
  for (int off = 1; off < 64; off <<= 1) {
    int cu = __shfl_up(ci, off, 64);
    if (lane >= off) ci += cu;
  }
  int cex = ci - ct;
  int r1 = kk, r2 = nv - kk;
  // locate boundary bins; pack (bin<<12)|cex_at_bin, broadcast via max-reduce
  int p1 = -1, p2 = -1;
  {
    int run = cex;
#pragma unroll
    for (int i = 0; i < 16; ++i) {
      int cc = c[i];
      if (run < r1 && r1 <= run + cc) p1 = ((lane * 16 + i) << 12) | run;
      if (run < r2 && r2 <= run + cc) p2 = ((lane * 16 + i) << 12) | run;
      run += cc;
    }
  }
#pragma unroll
  for (int off = 32; off > 0; off >>= 1) {
    p1 = max(p1, __shfl_xor(p1, off, 64));
    p2 = max(p2, __shfl_xor(p2, off, 64));
  }
  int b1 = p1 >> 12, cex1 = p1 & 4095;
  int b2 = p2 >> 12, cex2 = p2 & 4095;
  // predicated in-register sums
  float s1 = 0.f, s2 = 0.f, tm = 0.f;
  int c1 = 0, c2 = 0;
#pragma unroll
  for (int i = 0; i < 16; ++i) {
    int b = bn[i];
    float v = vv[i];
    if (b == b1) { s1 += v; c1++; }
    if (b == b2) { s2 += v; c2++; }
    if (b > b1 && b < b2) tm += v;
  }
#pragma unroll
  for (int off = 32; off > 0; off >>= 1) {
    s1 += __shfl_xor(s1, off, 64);
    s2 += __shfl_xor(s2, off, 64);
    tm += __shfl_xor(tm, off, 64);
    c1 += __shfl_xor(c1, off, 64);
    c2 += __shfl_xor(c2, off, 64);
  }
  float mid;
  if (b1 == b2) {
    mid = (float)(r2 - r1) * (s1 / (float)c1);
  } else {
    mid = (float)(cex1 + c1 - r1) * (s1 / (float)c1) + tm +
          (float)(r2 - cex2) * (s2 / (float)c2);
  }
  if (lane == 0) {
    agg[(batch << 10) + h] = mid / (float)(nv - 2 * kk);
  }
}

// ---------------- Decode (fused): one block per batch ----------------
__global__ __launch_bounds__(256) void decode(const float* __restrict__ agg,
                                              const float* __restrict__ W3,
                                              const float* __restrict__ b3,
                                              const float* __restrict__ W4,
                                              const float* __restrict__ b4,
                                              float* __restrict__ outp) {
  __shared__ float al[1024];
  __shared__ float a3[1024];
  __shared__ float red[4][10];
  int b = blockIdx.x, t = threadIdx.x, lane = t & 63, w = t >> 6;
  for (int i = t; i < 1024; i += 256) al[i] = agg[(b << 10) + i];
  __syncthreads();
#pragma unroll
  for (int jj = 0; jj < 4; ++jj) {
    int h = jj * 256 + t;
    float acc = b3[h];
#pragma unroll 8
    for (int k2 = 0; k2 < 1024; ++k2) acc = fmaf(al[k2], W3[(size_t)k2 * 1024 + h], acc);
    a3[h] = fmaxf(acc, 0.f);
  }
  __syncthreads();
  float part[10];
#pragma unroll
  for (int o = 0; o < 10; ++o) part[o] = 0.f;
#pragma unroll
  for (int jj = 0; jj < 4; ++jj) {
    int h2 = jj * 256 + t;
    float a = a3[h2];
#pragma unroll
    for (int o = 0; o < 10; ++o) part[o] = fmaf(a, W4[h2 * 10 + o], part[o]);
  }
#pragma unroll
  for (int o = 0; o < 10; ++o)
#pragma unroll
    for (int off = 32; off > 0; off >>= 1) part[o] += __shfl_xor(part[o], off, 64);
  if (lane == 0)
#pragma unroll
    for (int o = 0; o < 10; ++o) red[w][o] = part[o];
  __syncthreads();
  if (t < 10) outp[b * 10 + t] = b4[t] + red[0][t] + red[1][t] + red[2][t] + red[3][t];
}

extern "C" void kernel_launch(void* const* d_in, const int* in_sizes, int n_in,
                              void* d_out, int out_size, void* d_ws, size_t ws_size,
                              hipStream_t stream) {
  const float* X = (const float*)d_in[0];
  const float* mask = (const float*)d_in[1];
  const float* W1 = (const float*)d_in[2];
  const float* b1 = (const float*)d_in[3];
  const float* W2 = (const float*)d_in[4];
  const float* b2 = (const float*)d_in[5];
  const float* W3 = (const float*)d_in[6];
  const float* b3 = (const float*)d_in[7];
  const float* W4 = (const float*)d_in[8];
  const float* b4 = (const float*)d_in[9];
  float* outp = (float*)d_out;
  char* ws = (char*)d_ws;

  _Float16* X16 = (_Float16*)(ws);
  _Float16* H1 = (_Float16*)(ws + 67108864ull);
  _Float16* encT = (_Float16*)(ws + 201326592ull);
  _Float16* W1T = (_Float16*)(ws + 335544320ull);
  _Float16* W2T = (_Float16*)(ws + 336592896ull);
  float* agg = (float*)(ws + 338690048ull);
  int* nv_arr = (int*)(ws + 339214336ull);
  int* k_arr = (int*)(ws + 339214592ull);

  prep_nv<<<64, 64, 0, stream>>>(mask, nv_arr, k_arr);
  preprocess<<<16768, 256, 0, stream>>>(X, X16, W1, W1T, W2, W2T, nv_arr);
  gemm_kernel<512, 1><<<4096, 256, 0, stream>>>(W1T, X16, b1, nv_arr, H1);
  gemm_kernel<1024, 2><<<4096, 256, 0, stream>>>(H1, W2T, b2, nv_arr, encT);
  trim_kernel<<<16384, 256, 0, stream>>>(encT, nv_arr, k_arr, agg);
  decode<<<64, 256, 0, stream>>>(agg, W3, b3, W4, b4, outp);
}

// Round 7
// 542.243 us; speedup vs baseline: 1.3915x; 1.3915x over previous
//
#include <hip/hip_runtime.h>

// DeepSet trimmed-mean pipeline, fp16 MFMA path.
// ws layout (bytes), total ~339.3 MB:
//   X16   @ 0          (64 MB)   fp16 [65536][512]
//   H1    @ 64MB       (128 MB)  fp16 [65536][1024]
//   encT  @ 192MB      (128 MB)  fp16 [64][1024 h][1024 n]
//   W1T   @ 320MB      (1 MB)    fp16 [1024][512]
//   W2T   @ 321MB      (2 MB)    fp16 [1024][1024]
//   agg   @ 323MB      (256 KB)  f32 [64][1024]
//   A3    @ +256KB     (256 KB)  f32 [64][1024]
//   nv,k  @ +512KB     (tiny)

typedef _Float16 half8  __attribute__((ext_vector_type(8)));
typedef _Float16 half4v __attribute__((ext_vector_type(4)));
typedef float    floatx4 __attribute__((ext_vector_type(4)));

#define GLD_LDS(g, l)                                                                     \
  __builtin_amdgcn_global_load_lds((const __attribute__((address_space(1))) void*)(g),    \
                                   (__attribute__((address_space(3))) void*)(l), 16, 0, 0)

// ---------------- P0: num_valid / k per batch ----------------
__global__ void prep_nv(const float* __restrict__ mask, int* __restrict__ nv_arr,
                        int* __restrict__ k_arr) {
  int b = blockIdx.x, lane = threadIdx.x;  // 64 threads
  const float4* mp = (const float4*)(mask + (b << 10));
  float s = 0.f;
#pragma unroll
  for (int i = 0; i < 4; ++i) {
    float4 v = mp[lane + i * 64];
    s += v.x + v.y + v.z + v.w;
  }
#pragma unroll
  for (int off = 32; off > 0; off >>= 1) s += __shfl_xor(s, off, 64);
  if (lane == 0) {
    int nv = (int)(s + 0.5f);
    int kk = (int)((float)nv * 0.1f);  // matches reference float32 * 0.1 -> int
    nv_arr[b] = nv;
    k_arr[b] = kk;
  }
}

// ---------------- P1 (merged): X conv (+ragged skip) & both W transposes --------
__device__ __forceinline__ void transpose_body(const float* __restrict__ W,
                                               _Float16* __restrict__ WT, int R, int C,
                                               int r0, int c0, _Float16 (*tile)[65]) {
  for (int i = threadIdx.x; i < 4096; i += 256) {
    int r = i >> 6, c = i & 63;
    tile[r][c] = (_Float16)W[(size_t)(r0 + r) * C + c0 + c];
  }
  __syncthreads();
  for (int i = threadIdx.x; i < 4096; i += 256) {
    int c = i >> 6, r = i & 63;
    WT[(size_t)(c0 + c) * R + r0 + r] = tile[r][c];
  }
}

__global__ __launch_bounds__(256) void preprocess(
    const float* __restrict__ X, _Float16* __restrict__ X16,
    const float* __restrict__ W1, _Float16* __restrict__ W1T,
    const float* __restrict__ W2, _Float16* __restrict__ W2T,
    const int* __restrict__ nv_arr) {
  __shared__ _Float16 tile[64][65];
  int bid = blockIdx.x;
  if (bid < 16384) {
    // conv X fp32->fp16; block covers rows 4*bid..4*bid+3 of one batch.
    int n0 = (bid << 2) & 1023;
    int batch = bid >> 8;
    int nv = nv_arr[batch];
    if (n0 >= ((nv + 127) & ~127)) return;  // rows never read by GEMM1
    int i = (bid * 256 + threadIdx.x) * 8;
    float4 a = *(const float4*)(X + i);
    float4 c = *(const float4*)(X + i + 4);
    half8 h;
    h[0] = (_Float16)a.x; h[1] = (_Float16)a.y; h[2] = (_Float16)a.z; h[3] = (_Float16)a.w;
    h[4] = (_Float16)c.x; h[5] = (_Float16)c.y; h[6] = (_Float16)c.z; h[7] = (_Float16)c.w;
    *(half8*)(X16 + i) = h;
  } else if (bid < 16384 + 128) {
    int id = bid - 16384;  // W1: R=512, C=1024; 8 x 16 tiles
    transpose_body(W1, W1T, 512, 1024, (id & 7) * 64, (id >> 3) * 64, tile);
  } else {
    int id = bid - 16512;  // W2: R=1024, C=1024; 16 x 16 tiles
    transpose_body(W2, W2T, 1024, 1024, (id & 15) * 64, (id >> 4) * 64, tile);
  }
}

// ---------------- GEMM: D[i][j] = sum_k Aop[i][k]*Bop[j][k] ----------------
// 128x128 tile, BK=64 (32 MFMA per barrier). [R4 config — measured best: 154 us,
// 0 bank conflicts, FETCH ~88 MB. BK=32 dbuf (R5) regressed: conflicts returned.]
// XCD-aware grid: with round-robin workgroup->XCD (bid%8), the 8 blocks sharing a
// fat-operand tile are consecutive slots on ONE XCD: fat = ((bid>>6)<<3)|(bid&7),
// thin = (bid>>3)&7 -> fat tile fetched into exactly one XCD L2, once.
// MODE 1: i=h(thin), j=m(fat). out = relu(D+bias[i]) -> H1[m][h].
// MODE 2: i=m(fat), j=h(thin). out = D + bias[j] -> encT[b][h][n].
// LDS: 128 rows x 64 halves; 16B chunk c of row r at slot (c ^ (r&7)), permutation
// applied to the GLOBAL source address (global_load_lds lands lane-contiguous).
template <int KDIM, int MODE>
__global__ __launch_bounds__(256, 3) void gemm_kernel(
    const _Float16* __restrict__ Aop, const _Float16* __restrict__ Bop,
    const float* __restrict__ bias, const int* __restrict__ nv_arr,
    _Float16* __restrict__ outp) {
  __shared__ __align__(16) _Float16 ldsA[128 * 64];
  __shared__ __align__(16) _Float16 ldsB[128 * 64];
  int i0, j0;
  int bid = blockIdx.x;
  int fat = (((bid >> 6) << 3) | (bid & 7)) * 128;
  int thin = ((bid >> 3) & 7) * 128;
  if (MODE == 1) {
    i0 = thin; j0 = fat;
    if ((j0 & 1023) >= nv_arr[j0 >> 10]) return;
  } else {
    i0 = fat; j0 = thin;
    if ((i0 & 1023) >= nv_arr[i0 >> 10]) return;
  }
  const int t = threadIdx.x, lane = t & 63;
  const int wv = t >> 6, wi = wv & 1, wj = wv >> 1;
  const int lr = lane & 15, q = lane >> 4;

  floatx4 acc[4][4] = {};

  // staging: chunk idx = r*256 + t (r=0..3) per operand; row = idx>>3, slot = idx&7,
  // global chunk gch = slot ^ (row&7). gch is independent of r.
  const int gch = (t & 7) ^ ((t >> 3) & 7);
  const _Float16* gA[4];
  const _Float16* gB[4];
  _Float16* lA[4];
  _Float16* lB[4];
#pragma unroll
  for (int r = 0; r < 4; ++r) {
    int row = r * 32 + (t >> 3);
    gA[r] = Aop + (size_t)(i0 + row) * KDIM + gch * 8;
    gB[r] = Bop + (size_t)(j0 + row) * KDIM + gch * 8;
    lA[r] = ldsA + (r * 256 + (t & ~63)) * 8;
    lB[r] = ldsB + (r * 256 + (t & ~63)) * 8;
  }

  int aoff[4], boff[4];
#pragma unroll
  for (int mi = 0; mi < 4; ++mi) {
    int row = wi * 64 + mi * 16 + lr;
    aoff[mi] = row * 64 + ((q ^ (row & 7)) * 8);
  }
#pragma unroll
  for (int nj = 0; nj < 4; ++nj) {
    int row = wj * 64 + nj * 16 + lr;
    boff[nj] = row * 64 + ((q ^ (row & 7)) * 8);
  }

  for (int kt = 0; kt < KDIM / 64; ++kt) {
#pragma unroll
    for (int r = 0; r < 4; ++r) GLD_LDS(gA[r], lA[r]);
#pragma unroll
    for (int r = 0; r < 4; ++r) GLD_LDS(gB[r], lB[r]);
#pragma unroll
    for (int r = 0; r < 4; ++r) { gA[r] += 64; gB[r] += 64; }
    __syncthreads();
#pragma unroll
    for (int kk = 0; kk < 2; ++kk) {
      half8 af[4], bf[4];
#pragma unroll
      for (int mi = 0; mi < 4; ++mi) af[mi] = *(const half8*)&ldsA[aoff[mi] ^ (kk * 32)];
#pragma unroll
      for (int nj = 0; nj < 4; ++nj) bf[nj] = *(const half8*)&ldsB[boff[nj] ^ (kk * 32)];
#pragma unroll
      for (int mi = 0; mi < 4; ++mi)
#pragma unroll
        for (int nj = 0; nj < 4; ++nj)
          acc[mi][nj] =
              __builtin_amdgcn_mfma_f32_16x16x32_f16(af[mi], bf[nj], acc[mi][nj], 0, 0, 0);
    }
    __syncthreads();
  }

  // epilogue: lane holds rows i = base..base+3 (contiguous), col j = lr per 16x16 tile
  if (MODE == 1) {
#pragma unroll
    for (int mi = 0; mi < 4; ++mi) {
      int ih = i0 + wi * 64 + mi * 16 + q * 4;
      floatx4 bb = *(const floatx4*)&bias[ih];
#pragma unroll
      for (int nj = 0; nj < 4; ++nj) {
        int j = j0 + wj * 64 + nj * 16 + lr;
        floatx4 v = acc[mi][nj];
        half4v hv;
#pragma unroll
        for (int r = 0; r < 4; ++r) hv[r] = (_Float16)fmaxf(v[r] + bb[r], 0.f);
        *(half4v*)&outp[(size_t)j * 1024 + ih] = hv;  // H1[m][h..h+3]
      }
    }
  } else {
#pragma unroll
    for (int nj = 0; nj < 4; ++nj) {
      int j = j0 + wj * 64 + nj * 16 + lr;  // h
      float bj = bias[j];
#pragma unroll
      for (int mi = 0; mi < 4; ++mi) {
        int im = i0 + wi * 64 + mi * 16 + q * 4;  // m
        int bb = im >> 10, n = im & 1023;
        floatx4 v = acc[mi][nj];
        half4v hv;
#pragma unroll
        for (int r = 0; r < 4; ++r) hv[r] = (_Float16)(v[r] + bj);
        *(half4v*)&outp[((size_t)bb << 20) + ((size_t)j << 10) + (size_t)n] = hv;
      }
    }
  }
}

// ---------------- Trim v3: count-only histogram + in-register sums ----------------
// One wave per column (b,h). 1024 u32 count bins (16 KB/block -> 10 blocks/CU).
// Locate boundary bins from count scan; all sums (s(b1), s(b2), mid-sum) computed
// in-register via predicated wave reductions over the 16 loaded values/lane.
// Physical slot of logical uint4-chunk j of lane L: L*4 + (j ^ ((L>>1)&3))  (2-way
// free bank pattern for the b128 init/readback).
#define NB 1024
__global__ __launch_bounds__(256) void trim_kernel(const _Float16* __restrict__ encT,
                                                   const int* __restrict__ nv_arr,
                                                   const int* __restrict__ k_arr,
                                                   float* __restrict__ agg) {
  __shared__ unsigned int cnt[4 * NB];  // 16 KB, wave-private slices
  int t = threadIdx.x, lane = t & 63, w = t >> 6;
  int blk = blockIdx.x;
  int batch = blk >> 8;
  int h = ((blk & 255) << 2) + w;
  unsigned int* cw = cnt + w * NB;
  uint4* cp = (uint4*)cw;
  {
    uint4 z = {0u, 0u, 0u, 0u};
#pragma unroll
    for (int i = 0; i < 4; ++i) cp[lane * 4 + (i ^ ((lane >> 1) & 3))] = z;
  }

  int nv = nv_arr[batch], kk = k_arr[batch];
  const _Float16* col = encT + ((size_t)batch << 20) + ((size_t)h << 10);
  const uint4* p = (const uint4*)col + lane * 2;
  uint4 u0 = p[0], u1 = p[1];
  unsigned vals[8] = {u0.x, u0.y, u0.z, u0.w, u1.x, u1.y, u1.z, u1.w};
  int nvalid = nv - lane * 16;  // may be <=0 or >=16

  float vv[16];
  int bn[16];
#pragma unroll
  for (int d = 0; d < 8; ++d) {
    unsigned u = vals[d];
#pragma unroll
    for (int sub = 0; sub < 2; ++sub) {
      int idx = d * 2 + sub;
      unsigned short bits = (unsigned short)(sub ? (u >> 16) : (u & 0xffffu));
      _Float16 hvv;
      __builtin_memcpy(&hvv, &bits, 2);
      float v = (float)hvv;
      if (idx < nvalid) {
        v = fminf(fmaxf(v, -8.0f), 7.999f);
        int bin = (int)((v + 8.0f) * 64.0f);
        bin = min(NB - 1, bin);
        vv[idx] = v;
        bn[idx] = bin;
        int Lb = bin >> 4, jc = (bin >> 2) & 3;
        int phys = ((Lb << 2) + (jc ^ ((Lb >> 1) & 3))) * 4 + (bin & 3);
        atomicAdd(&cw[phys], 1u);
      } else {
        vv[idx] = 0.f;
        bn[idx] = -1;
      }
    }
  }

  // readback own 16 counts (logical bins [lane*16, lane*16+16))
  int c[16];
  {
    uint4 rb[4];
#pragma unroll
    for (int i = 0; i < 4; ++i) rb[i] = cp[lane * 4 + (i ^ ((lane >> 1) & 3))];
#pragma unroll
    for (int i = 0; i < 4; ++i) {
      c[4 * i] = (int)rb[i].x; c[4 * i + 1] = (int)rb[i].y;
      c[4 * i + 2] = (int)rb[i].z; c[4 * i + 3] = (int)rb[i].w;
    }
  }
  int ct = 0;
#pragma unroll
  for (int i = 0; i < 16; ++i) ct += c[i];
  // exclusive scan of chunk totals across lanes
  int ci = ct;
#pragma unroll
  for (int off = 1; off < 64; off <<= 1) {
    int cu = __shfl_up(ci, off, 64);
    if (lane >= off) ci += cu;
  }
  int cex = ci - ct;
  int r1 = kk, r2 = nv - kk;
  // locate boundary bins; pack (bin<<12)|cex_at_bin, broadcast via max-reduce
  int p1 = -1, p2 = -1;
  {
    int run = cex;
#pragma unroll
    for (int i = 0; i < 16; ++i) {
      int cc = c[i];
      if (run < r1 && r1 <= run + cc) p1 = ((lane * 16 + i) << 12) | run;
      if (run < r2 && r2 <= run + cc) p2 = ((lane * 16 + i) << 12) | run;
      run += cc;
    }
  }
#pragma unroll
  for (int off = 32; off > 0; off >>= 1) {
    p1 = max(p1, __shfl_xor(p1, off, 64));
    p2 = max(p2, __shfl_xor(p2, off, 64));
  }
  int b1 = p1 >> 12, cex1 = p1 & 4095;
  int b2 = p2 >> 12, cex2 = p2 & 4095;
  // predicated in-register sums
  float s1 = 0.f, s2 = 0.f, tm = 0.f;
  int c1 = 0, c2 = 0;
#pragma unroll
  for (int i = 0; i < 16; ++i) {
    int b = bn[i];
    float v = vv[i];
    if (b == b1) { s1 += v; c1++; }
    if (b == b2) { s2 += v; c2++; }
    if (b > b1 && b < b2) tm += v;
  }
#pragma unroll
  for (int off = 32; off > 0; off >>= 1) {
    s1 += __shfl_xor(s1, off, 64);
    s2 += __shfl_xor(s2, off, 64);
    tm += __shfl_xor(tm, off, 64);
    c1 += __shfl_xor(c1, off, 64);
    c2 += __shfl_xor(c2, off, 64);
  }
  float mid;
  if (b1 == b2) {
    mid = (float)(r2 - r1) * (s1 / (float)c1);
  } else {
    mid = (float)(cex1 + c1 - r1) * (s1 / (float)c1) + tm +
          (float)(r2 - cex2) * (s2 / (float)c2);
  }
  if (lane == 0) {
    agg[(batch << 10) + h] = mid / (float)(nv - 2 * kk);
  }
}

// ---------------- Decode 1 (K-split GEMV): A3 = relu(agg @ W3 + b3) ----------------
// grid (64 batches, 16 h-tiles), 256 threads. Thread (hl=t&63, ks=t>>6) computes
// h = 64*hb+hl over K-range [256*ks, 256*ks+256): 4x K-split -> 4x fewer serial
// loads/thread than one-thread-per-h; 1024 blocks (16 waves/CU) for latency hiding.
__global__ __launch_bounds__(256) void decode1(const float* __restrict__ agg,
                                               const float* __restrict__ W3,
                                               const float* __restrict__ b3,
                                               float* __restrict__ A3) {
  __shared__ float al[1024];
  __shared__ float red[256];
  int b = blockIdx.x, hb = blockIdx.y, t = threadIdx.x;
  for (int i = t; i < 1024; i += 256) al[i] = agg[(b << 10) + i];
  __syncthreads();
  int hl = t & 63, ks = t >> 6;
  int h = hb * 64 + hl;
  const float* wp = W3 + (size_t)(ks * 256) * 1024 + h;
  const float* ap = al + ks * 256;
  float acc = 0.f;
#pragma unroll 8
  for (int k = 0; k < 256; ++k) acc = fmaf(ap[k], wp[(size_t)k * 1024], acc);
  red[t] = acc;
  __syncthreads();
  if (t < 64) {
    float s = red[t] + red[t + 64] + red[t + 128] + red[t + 192] + b3[hb * 64 + t];
    A3[(b << 10) + hb * 64 + t] = fmaxf(s, 0.f);
  }
}

__global__ void decode2(const float* __restrict__ A3, const float* __restrict__ W4,
                        const float* __restrict__ b4, float* __restrict__ outp) {
  __shared__ float red[4][10];
  int b = blockIdx.x, t = threadIdx.x, lane = t & 63, w = t >> 6;
  float part[10];
#pragma unroll
  for (int o = 0; o < 10; ++o) part[o] = 0.f;
#pragma unroll
  for (int jj = 0; jj < 4; ++jj) {
    int h2 = jj * 256 + t;
    float a = A3[(b << 10) + h2];
#pragma unroll
    for (int o = 0; o < 10; ++o) part[o] = fmaf(a, W4[h2 * 10 + o], part[o]);
  }
#pragma unroll
  for (int o = 0; o < 10; ++o)
#pragma unroll
    for (int off = 32; off > 0; off >>= 1) part[o] += __shfl_xor(part[o], off, 64);
  if (lane == 0)
#pragma unroll
    for (int o = 0; o < 10; ++o) red[w][o] = part[o];
  __syncthreads();
  if (t < 10) outp[b * 10 + t] = b4[t] + red[0][t] + red[1][t] + red[2][t] + red[3][t];
}

extern "C" void kernel_launch(void* const* d_in, const int* in_sizes, int n_in,
                              void* d_out, int out_size, void* d_ws, size_t ws_size,
                              hipStream_t stream) {
  const float* X = (const float*)d_in[0];
  const float* mask = (const float*)d_in[1];
  const float* W1 = (const float*)d_in[2];
  const float* b1 = (const float*)d_in[3];
  const float* W2 = (const float*)d_in[4];
  const float* b2 = (const float*)d_in[5];
  const float* W3 = (const float*)d_in[6];
  const float* b3 = (const float*)d_in[7];
  const float* W4 = (const float*)d_in[8];
  const float* b4 = (const float*)d_in[9];
  float* outp = (float*)d_out;
  char* ws = (char*)d_ws;

  _Float16* X16 = (_Float16*)(ws);
  _Float16* H1 = (_Float16*)(ws + 67108864ull);
  _Float16* encT = (_Float16*)(ws + 201326592ull);
  _Float16* W1T = (_Float16*)(ws + 335544320ull);
  _Float16* W2T = (_Float16*)(ws + 336592896ull);
  float* agg = (float*)(ws + 338690048ull);
  float* A3 = (float*)(ws + 338952192ull);
  int* nv_arr = (int*)(ws + 339214336ull);
  int* k_arr = (int*)(ws + 339214592ull);

  prep_nv<<<64, 64, 0, stream>>>(mask, nv_arr, k_arr);
  preprocess<<<16768, 256, 0, stream>>>(X, X16, W1, W1T, W2, W2T, nv_arr);
  gemm_kernel<512, 1><<<4096, 256, 0, stream>>>(W1T, X16, b1, nv_arr, H1);
  gemm_kernel<1024, 2><<<4096, 256, 0, stream>>>(H1, W2T, b2, nv_arr, encT);
  trim_kernel<<<16384, 256, 0, stream>>>(encT, nv_arr, k_arr, agg);
  decode1<<<dim3(64, 16), 256, 0, stream>>>(agg, W3, b3, A3);
  decode2<<<64, 256, 0, stream>>>(A3, W4, b4, outp);
}